// Round 1
// baseline (555.347 us; speedup 1.0000x reference)
//
#include <hip/hip_runtime.h>
#include <math.h>

#define C_CLS 1000
#define M_MEM 50
#define D_DIM 1024
#define L_TOK 196
#define SOFTMAX_LOCAL_F 50.0f

// ws layout (as float*):
//   ((int*)ws)[0] = pseudo, [1] = slot, [2] = do_write
//   ws[16 .. 16+1024) = normalized att vector

__global__ __launch_bounds__(256) void prep_kernel(
    const float* __restrict__ init_pred,   // [C]
    const float* __restrict__ loc,         // [L, D]
    const float* __restrict__ text_feat,   // [C, D]
    const float* __restrict__ ent_mem,     // [C, M]
    const int*   __restrict__ count,       // [C, 1]
    float* __restrict__ ws)
{
    __shared__ float s_val[256];
    __shared__ int   s_idx[256];
    __shared__ float s_red[256];
    __shared__ float s_cos[L_TOK];
    __shared__ float s_w[L_TOK];

    const int tid = threadIdx.x;

    // ---- Phase 1: argmax (first-index ties) + entropy over init_pred ----
    float best = -INFINITY; int bidx = 0x7fffffff;
    float entacc = 0.0f;
    for (int i = tid; i < C_CLS; i += 256) {
        float p = init_pred[i];
        entacc -= p * logf(p + 1e-8f);
        if (p > best || (p == best && i < bidx)) { best = p; bidx = i; }
    }
    s_val[tid] = best; s_idx[tid] = bidx; s_red[tid] = entacc;
    __syncthreads();
    for (int s = 128; s > 0; s >>= 1) {
        if (tid < s) {
            float v2 = s_val[tid + s]; int i2 = s_idx[tid + s];
            if (v2 > s_val[tid] || (v2 == s_val[tid] && i2 < s_idx[tid])) {
                s_val[tid] = v2; s_idx[tid] = i2;
            }
            s_red[tid] += s_red[tid + s];
        }
        __syncthreads();
    }
    const int   pseudo = s_idx[0];
    const float value  = s_val[0];
    const float ent    = s_red[0];
    // (all threads read s_red[0] here; a later barrier precedes any rewrite)

    const float* t = text_feat + (size_t)pseudo * D_DIM;

    // ---- Phase 2: cos[l] = loc[l] . t  (per-wave rows, lane-strided dot) ----
    const int wave = tid >> 6, lane = tid & 63;
    for (int l = wave; l < L_TOK; l += 4) {
        const float* row = loc + (size_t)l * D_DIM;
        float acc = 0.0f;
        for (int k = lane; k < D_DIM; k += 64) acc += row[k] * t[k];
        for (int off = 32; off > 0; off >>= 1) acc += __shfl_down(acc, off);
        if (lane == 0) s_cos[l] = acc;
    }
    __syncthreads();

    // ---- Phase 3: softmax over 196 logits ----
    float m = -INFINITY;
    for (int l = tid; l < L_TOK; l += 256) m = fmaxf(m, s_cos[l] * SOFTMAX_LOCAL_F);
    s_red[tid] = m; __syncthreads();
    for (int s = 128; s > 0; s >>= 1) {
        if (tid < s) s_red[tid] = fmaxf(s_red[tid], s_red[tid + s]);
        __syncthreads();
    }
    const float mx = s_red[0];
    __syncthreads();
    float sacc = 0.0f;
    for (int l = tid; l < L_TOK; l += 256) {
        float e = expf(s_cos[l] * SOFTMAX_LOCAL_F - mx);
        s_w[l] = e; sacc += e;
    }
    s_red[tid] = sacc; __syncthreads();
    for (int s = 128; s > 0; s >>= 1) {
        if (tid < s) s_red[tid] += s_red[tid + s];
        __syncthreads();
    }
    const float inv_sum = 1.0f / s_red[0];
    __syncthreads();

    // att[d] = (sum_l w[l] * loc[l][d]) * inv_sum ; coalesced column reads
    float att[4]; float nacc = 0.0f;
    #pragma unroll
    for (int q = 0; q < 4; ++q) {
        const int d = tid + q * 256;
        float a = 0.0f;
        for (int l = 0; l < L_TOK; ++l) a += s_w[l] * loc[(size_t)l * D_DIM + d];
        a *= inv_sum;
        att[q] = a; nacc += a * a;
    }
    s_red[tid] = nacc; __syncthreads();
    for (int s = 128; s > 0; s >>= 1) {
        if (tid < s) s_red[tid] += s_red[tid + s];
        __syncthreads();
    }
    const float inv_norm = 1.0f / sqrtf(s_red[0]);
    #pragma unroll
    for (int q = 0; q < 4; ++q) {
        const int d = tid + q * 256;
        ws[16 + d] = att[q] * inv_norm;
    }

    // ---- Phase 4: slot / do_write decision (thread 0, exact tie semantics) ----
    if (tid == 0) {
        const int cnt = count[pseudo];
        const bool full = cnt >= M_MEM;
        const float* erow = ent_mem + (size_t)pseudo * M_MEM;
        float emax = erow[0]; int worst = 0;
        for (int j = 1; j < M_MEM; ++j) {
            float e = erow[j];
            if (e > emax) { emax = e; worst = j; }   // strict > => first max index
        }
        const bool replace_ok = ent < emax;
        const bool do_write = (value > 0.0f) && (full ? replace_ok : true);
        int slot = full ? worst : min(max(cnt, 0), M_MEM - 1);
        int* wsi = (int*)ws;
        wsi[0] = pseudo; wsi[1] = slot; wsi[2] = do_write ? 1 : 0;
    }
}

// out[c, 0:50, :]  = image_feature_memory[c]
// out[c, 50:100,:] = local_feature_memory[c]
__global__ __launch_bounds__(256) void copy_kernel(
    const float4* __restrict__ img,
    const float4* __restrict__ locm,
    float4* __restrict__ out)
{
    const int bid  = blockIdx.x;
    const int c    = bid >> 1;
    const int half = bid & 1;
    const int n = M_MEM * D_DIM / 4;                         // 12800 float4 per chunk
    const float4* src = (half ? locm : img) + (size_t)c * n;
    float4* dst = out + (size_t)c * (2 * n) + (size_t)half * n;
    for (int i = threadIdx.x; i < n; i += 256) dst[i] = src[i];
}

__global__ __launch_bounds__(256) void row_write_kernel(
    const float* __restrict__ g,
    const float* __restrict__ ws,
    float* __restrict__ out)
{
    const int* wsi = (const int*)ws;
    if (!wsi[2]) return;
    const int pseudo = wsi[0], slot = wsi[1];
    float* base = out + (size_t)pseudo * (2 * M_MEM * D_DIM);
    for (int d = threadIdx.x; d < D_DIM; d += 256) {
        base[(size_t)slot * D_DIM + d]           = g[d];
        base[(size_t)(M_MEM + slot) * D_DIM + d] = ws[16 + d];
    }
}

extern "C" void kernel_launch(void* const* d_in, const int* in_sizes, int n_in,
                              void* d_out, int out_size, void* d_ws, size_t ws_size,
                              hipStream_t stream) {
    const float* init_pred = (const float*)d_in[0];   // (1, C)
    const float* g         = (const float*)d_in[1];   // (1, D)
    const float* loc       = (const float*)d_in[2];   // (1, L, D)
    const float* text_feat = (const float*)d_in[3];   // (C, D)
    const float* img_mem   = (const float*)d_in[4];   // (C, M, D)
    const float* loc_mem   = (const float*)d_in[5];   // (C, M, D)
    const float* ent_mem   = (const float*)d_in[6];   // (C, M)
    const int*   count     = (const int*)d_in[7];     // (C, 1)
    float* out = (float*)d_out;
    float* ws  = (float*)d_ws;

    prep_kernel<<<1, 256, 0, stream>>>(init_pred, loc, text_feat, ent_mem, count, ws);
    copy_kernel<<<2 * C_CLS, 256, 0, stream>>>(
        (const float4*)img_mem, (const float4*)loc_mem, (float4*)out);
    row_write_kernel<<<1, 256, 0, stream>>>(g, ws, out);
}

// Round 2
// 195.207 us; speedup vs baseline: 2.8449x; 2.8449x over previous
//
#include <hip/hip_runtime.h>
#include <math.h>

#define C_CLS 1000
#define M_MEM 50
#define D_DIM 1024
#define L_TOK 196
#define SOFTMAX_LOCAL_F 50.0f

// ws layout (as float*):
//   ((int*)ws)[0] = pseudo, [1] = slot, [2] = do_write
//   ws[256 .. 256+1024) = normalized att vector (float4-aligned)

__global__ __launch_bounds__(1024) void prep_kernel(
    const float* __restrict__ init_pred,   // [C]
    const float* __restrict__ loc,         // [L, D]
    const float* __restrict__ text_feat,   // [C, D]
    const float* __restrict__ ent_mem,     // [C, M]
    const int*   __restrict__ count,       // [C, 1]
    float* __restrict__ ws)
{
    __shared__ float s_val[1024];
    __shared__ int   s_idx[1024];
    __shared__ float s_red[1024];
    __shared__ float s_cos[L_TOK];
    __shared__ float s_w[L_TOK];

    const int tid = threadIdx.x;

    // ---- Phase 1: argmax (first-index ties) + entropy over init_pred ----
    float best = -INFINITY; int bidx = 0x7fffffff;
    float entacc = 0.0f;
    for (int i = tid; i < C_CLS; i += 1024) {
        float p = init_pred[i];
        entacc -= p * logf(p + 1e-8f);
        if (p > best || (p == best && i < bidx)) { best = p; bidx = i; }
    }
    s_val[tid] = best; s_idx[tid] = bidx; s_red[tid] = entacc;
    __syncthreads();
    for (int s = 512; s > 0; s >>= 1) {
        if (tid < s) {
            float v2 = s_val[tid + s]; int i2 = s_idx[tid + s];
            if (v2 > s_val[tid] || (v2 == s_val[tid] && i2 < s_idx[tid])) {
                s_val[tid] = v2; s_idx[tid] = i2;
            }
            s_red[tid] += s_red[tid + s];
        }
        __syncthreads();
    }
    const int   pseudo = s_idx[0];
    const float value  = s_val[0];
    const float ent    = s_red[0];

    const float* t = text_feat + (size_t)pseudo * D_DIM;

    // ---- Phase 2: cos[l] = loc[l] . t  (16 waves, one row per wave) ----
    const int wave = tid >> 6, lane = tid & 63;
    for (int l = wave; l < L_TOK; l += 16) {
        const float* row = loc + (size_t)l * D_DIM;
        float acc = 0.0f;
        #pragma unroll
        for (int q = 0; q < D_DIM / 64; ++q) acc += row[lane + q * 64] * t[lane + q * 64];
        #pragma unroll
        for (int off = 32; off > 0; off >>= 1) acc += __shfl_down(acc, off);
        if (lane == 0) s_cos[l] = acc;
    }
    __syncthreads();   // also separates the s_red[0] read above from the rewrite below

    // ---- Phase 3: softmax over 196 logits ----
    float m = (tid < L_TOK) ? s_cos[tid] * SOFTMAX_LOCAL_F : -INFINITY;
    s_red[tid] = m; __syncthreads();
    for (int s = 512; s > 0; s >>= 1) {
        if (tid < s) s_red[tid] = fmaxf(s_red[tid], s_red[tid + s]);
        __syncthreads();
    }
    const float mx = s_red[0];
    __syncthreads();
    float sacc = 0.0f;
    if (tid < L_TOK) {
        float e = expf(s_cos[tid] * SOFTMAX_LOCAL_F - mx);
        s_w[tid] = e; sacc = e;
    }
    s_red[tid] = sacc; __syncthreads();
    for (int s = 512; s > 0; s >>= 1) {
        if (tid < s) s_red[tid] += s_red[tid + s];
        __syncthreads();
    }
    const float inv_sum = 1.0f / s_red[0];
    __syncthreads();

    // ---- Phase C: att[d] = inv_sum * sum_l w[l] * loc[l][d] (1024-wide, coalesced) ----
    float a = 0.0f;
    for (int l = 0; l < L_TOK; ++l) a += s_w[l] * loc[(size_t)l * D_DIM + tid];
    a *= inv_sum;
    s_red[tid] = a * a; __syncthreads();
    for (int s = 512; s > 0; s >>= 1) {
        if (tid < s) s_red[tid] += s_red[tid + s];
        __syncthreads();
    }
    const float inv_norm = rsqrtf(s_red[0]);
    ws[256 + tid] = a * inv_norm;

    // ---- Phase 4: slot / do_write decision (thread 0, exact tie semantics) ----
    if (tid == 0) {
        const int cnt = count[pseudo];
        const bool full = cnt >= M_MEM;
        const float* erow = ent_mem + (size_t)pseudo * M_MEM;
        float emax = erow[0]; int worst = 0;
        for (int j = 1; j < M_MEM; ++j) {
            float e = erow[j];
            if (e > emax) { emax = e; worst = j; }   // strict > => first max index
        }
        const bool replace_ok = ent < emax;
        const bool do_write = (value > 0.0f) && (full ? replace_ok : true);
        int slot = full ? worst : min(max(cnt, 0), M_MEM - 1);
        int* wsi = (int*)ws;
        wsi[0] = pseudo; wsi[1] = slot; wsi[2] = do_write ? 1 : 0;
    }
}

// out[c, 0:50, :]  = image_feature_memory[c]   (row `slot` of class `pseudo` replaced by g)
// out[c, 50:100,:] = local_feature_memory[c]   (row `slot` of class `pseudo` replaced by att)
__global__ __launch_bounds__(256) void copy_kernel(
    const float4* __restrict__ img,
    const float4* __restrict__ locm,
    const float4* __restrict__ g,          // [D/4]
    const float*  __restrict__ ws,
    float4* __restrict__ out)
{
    const int bid  = blockIdx.x;
    const int c    = bid >> 1;
    const int half = bid & 1;
    const int tid  = threadIdx.x;
    const int n    = M_MEM * D_DIM / 4;                      // 12800 float4 per chunk

    const int* wsi = (const int*)ws;
    const bool ov = (c == wsi[0]) && (wsi[2] != 0);          // overwrite this chunk's row?
    const int slot = wsi[1];

    const float4* src  = (half ? locm : img) + (size_t)c * n;
    const float4* repl = half ? (const float4*)(ws + 256) : g;
    float4* dst = out + (size_t)c * (2 * n) + (size_t)half * n;

    #pragma unroll 5
    for (int r = 0; r < M_MEM; ++r) {                        // one 1024-float row per iter
        float4 v;
        if (ov && r == slot) v = repl[tid];
        else                 v = src[r * 256 + tid];
        dst[r * 256 + tid] = v;
    }
}

extern "C" void kernel_launch(void* const* d_in, const int* in_sizes, int n_in,
                              void* d_out, int out_size, void* d_ws, size_t ws_size,
                              hipStream_t stream) {
    const float* init_pred = (const float*)d_in[0];   // (1, C)
    const float* g         = (const float*)d_in[1];   // (1, D)
    const float* loc       = (const float*)d_in[2];   // (1, L, D)
    const float* text_feat = (const float*)d_in[3];   // (C, D)
    const float* img_mem   = (const float*)d_in[4];   // (C, M, D)
    const float* loc_mem   = (const float*)d_in[5];   // (C, M, D)
    const float* ent_mem   = (const float*)d_in[6];   // (C, M)
    const int*   count     = (const int*)d_in[7];     // (C, 1)
    float* out = (float*)d_out;
    float* ws  = (float*)d_ws;

    prep_kernel<<<1, 1024, 0, stream>>>(init_pred, loc, text_feat, ent_mem, count, ws);
    copy_kernel<<<2 * C_CLS, 256, 0, stream>>>(
        (const float4*)img_mem, (const float4*)loc_mem, (const float4*)g, ws, (float4*)out);
}

// Round 4
// 157.694 us; speedup vs baseline: 3.5217x; 1.2379x over previous
//
#include <hip/hip_runtime.h>
#include <math.h>

#define C_CLS 1000
#define M_MEM 50
#define D_DIM 1024
#define L_TOK 196
#define SOFTMAX_LOCAL_F 50.0f

typedef float f32x4 __attribute__((ext_vector_type(4)));

// ws layout (as float*):
//   ((int*)ws)[0] = pseudo, [1] = slot, [2] = do_write
//   ws[256 .. 256+1024) = normalized att vector (float4-aligned)

__device__ __forceinline__ void prep_body(
    const float* __restrict__ init_pred,
    const float* __restrict__ loc,
    const float* __restrict__ text_feat,
    const float* __restrict__ ent_mem,
    const int*   __restrict__ count,
    float* __restrict__ ws)
{
    __shared__ float s_val[1024];
    __shared__ int   s_idx[1024];
    __shared__ float s_red[1024];
    __shared__ float s_cos[L_TOK];
    __shared__ float s_w[L_TOK];

    const int tid = threadIdx.x;

    // ---- Phase 1: argmax (first-index ties) + entropy over init_pred ----
    float best = -INFINITY; int bidx = 0x7fffffff;
    float entacc = 0.0f;
    for (int i = tid; i < C_CLS; i += 1024) {
        float p = init_pred[i];
        entacc -= p * logf(p + 1e-8f);
        if (p > best || (p == best && i < bidx)) { best = p; bidx = i; }
    }
    s_val[tid] = best; s_idx[tid] = bidx; s_red[tid] = entacc;
    __syncthreads();
    for (int s = 512; s > 0; s >>= 1) {
        if (tid < s) {
            float v2 = s_val[tid + s]; int i2 = s_idx[tid + s];
            if (v2 > s_val[tid] || (v2 == s_val[tid] && i2 < s_idx[tid])) {
                s_val[tid] = v2; s_idx[tid] = i2;
            }
            s_red[tid] += s_red[tid + s];
        }
        __syncthreads();
    }
    const int   pseudo = s_idx[0];
    const float value  = s_val[0];
    const float ent    = s_red[0];

    const float* t = text_feat + (size_t)pseudo * D_DIM;

    // ---- Phase 2: cos[l] = loc[l] . t  (16 waves, one row per wave) ----
    const int wave = tid >> 6, lane = tid & 63;
    for (int l = wave; l < L_TOK; l += 16) {
        const float* row = loc + (size_t)l * D_DIM;
        float acc = 0.0f;
        #pragma unroll
        for (int q = 0; q < D_DIM / 64; ++q) acc += row[lane + q * 64] * t[lane + q * 64];
        #pragma unroll
        for (int off = 32; off > 0; off >>= 1) acc += __shfl_down(acc, off);
        if (lane == 0) s_cos[l] = acc;
    }
    __syncthreads();   // also separates the s_red[0] read above from the rewrite below

    // ---- Phase 3: softmax over 196 logits ----
    float m = (tid < L_TOK) ? s_cos[tid] * SOFTMAX_LOCAL_F : -INFINITY;
    s_red[tid] = m; __syncthreads();
    for (int s = 512; s > 0; s >>= 1) {
        if (tid < s) s_red[tid] = fmaxf(s_red[tid], s_red[tid + s]);
        __syncthreads();
    }
    const float mx = s_red[0];
    __syncthreads();
    float sacc = 0.0f;
    if (tid < L_TOK) {
        float e = expf(s_cos[tid] * SOFTMAX_LOCAL_F - mx);
        s_w[tid] = e; sacc = e;
    }
    s_red[tid] = sacc; __syncthreads();
    for (int s = 512; s > 0; s >>= 1) {
        if (tid < s) s_red[tid] += s_red[tid + s];
        __syncthreads();
    }
    const float inv_sum = 1.0f / s_red[0];
    __syncthreads();

    // ---- Phase C: att[d] = inv_sum * sum_l w[l] * loc[l][d] (1024-wide, coalesced) ----
    float a = 0.0f;
    for (int l = 0; l < L_TOK; ++l) a += s_w[l] * loc[(size_t)l * D_DIM + tid];
    a *= inv_sum;
    s_red[tid] = a * a; __syncthreads();
    for (int s = 512; s > 0; s >>= 1) {
        if (tid < s) s_red[tid] += s_red[tid + s];
        __syncthreads();
    }
    const float inv_norm = rsqrtf(s_red[0]);
    ws[256 + tid] = a * inv_norm;

    // ---- Phase 4: slot / do_write decision (thread 0, exact tie semantics) ----
    if (tid == 0) {
        const int cnt = count[pseudo];
        const bool full = cnt >= M_MEM;
        const float* erow = ent_mem + (size_t)pseudo * M_MEM;
        float emax = erow[0]; int worst = 0;
        for (int j = 1; j < M_MEM; ++j) {
            float e = erow[j];
            if (e > emax) { emax = e; worst = j; }   // strict > => first max index
        }
        const bool replace_ok = ent < emax;
        const bool do_write = (value > 0.0f) && (full ? replace_ok : true);
        int slot = full ? worst : min(max(cnt, 0), M_MEM - 1);
        int* wsi = (int*)ws;
        wsi[0] = pseudo; wsi[1] = slot; wsi[2] = do_write ? 1 : 0;
    }
}

// Block 0: prep (decision + att vector -> ws).
// Blocks 1..2000: unconditional bank->out copy (no dependence on prep).
__global__ __launch_bounds__(1024) void fused_kernel(
    const float* __restrict__ init_pred,
    const float* __restrict__ loc,
    const float* __restrict__ text_feat,
    const float* __restrict__ ent_mem,
    const int*   __restrict__ count,
    const f32x4* __restrict__ img,
    const f32x4* __restrict__ locm,
    f32x4* __restrict__ out,
    float* __restrict__ ws)
{
    if (blockIdx.x == 0) {
        prep_body(init_pred, loc, text_feat, ent_mem, count, ws);
        return;
    }
    const int bid  = blockIdx.x - 1;                 // 0..1999
    const int c    = bid >> 1;
    const int half = bid & 1;
    const int n    = M_MEM * D_DIM / 4;              // 12800 f32x4 per chunk

    const f32x4* src = (half ? locm : img) + (size_t)c * n;
    f32x4* dst = out + (size_t)c * (2 * n) + (size_t)half * n;

    for (int i = threadIdx.x; i < n; i += 1024) {
        f32x4 v = __builtin_nontemporal_load(src + i);
        __builtin_nontemporal_store(v, dst + i);
    }
}

// Patch the two affected 4 KB rows after prep's decision is known.
__global__ __launch_bounds__(256) void row_write_kernel(
    const f32x4* __restrict__ g,           // [D/4]
    const float* __restrict__ ws,
    f32x4* __restrict__ out)
{
    const int* wsi = (const int*)ws;
    if (!wsi[2]) return;
    const int pseudo = wsi[0], slot = wsi[1];
    const f32x4* att = (const f32x4*)(ws + 256);
    f32x4* base = out + (size_t)pseudo * (2 * M_MEM * D_DIM / 4);
    const int tid = threadIdx.x;   // 256 threads x f32x4 = 1024 floats = one row
    base[(size_t)slot * (D_DIM / 4) + tid]           = g[tid];
    base[(size_t)(M_MEM + slot) * (D_DIM / 4) + tid] = att[tid];
}

extern "C" void kernel_launch(void* const* d_in, const int* in_sizes, int n_in,
                              void* d_out, int out_size, void* d_ws, size_t ws_size,
                              hipStream_t stream) {
    const float* init_pred = (const float*)d_in[0];   // (1, C)
    const float* g         = (const float*)d_in[1];   // (1, D)
    const float* loc       = (const float*)d_in[2];   // (1, L, D)
    const float* text_feat = (const float*)d_in[3];   // (C, D)
    const float* img_mem   = (const float*)d_in[4];   // (C, M, D)
    const float* loc_mem   = (const float*)d_in[5];   // (C, M, D)
    const float* ent_mem   = (const float*)d_in[6];   // (C, M)
    const int*   count     = (const int*)d_in[7];     // (C, 1)
    float* out = (float*)d_out;
    float* ws  = (float*)d_ws;

    fused_kernel<<<2 * C_CLS + 1, 1024, 0, stream>>>(
        init_pred, loc, text_feat, ent_mem, count,
        (const f32x4*)img_mem, (const f32x4*)loc_mem, (f32x4*)out, ws);
    row_write_kernel<<<1, 256, 0, stream>>>((const f32x4*)g, ws, (f32x4*)out);
}

// Round 5
// 142.957 us; speedup vs baseline: 3.8847x; 1.1031x over previous
//
#include <hip/hip_runtime.h>
#include <math.h>

#define C_CLS 1000
#define M_MEM 50
#define D_DIM 1024
#define L_TOK 196
#define SOFTMAX_LOCAL_F 50.0f

typedef float f32x4 __attribute__((ext_vector_type(4)));

// ws layout (as float*):
//   ((int*)ws)[0] = pseudo, [1] = slot, [2] = do_write
//   ws[256 .. 256+1024) = normalized att vector (float4-aligned)

__device__ __forceinline__ void prep_body(
    const float* __restrict__ init_pred,
    const float* __restrict__ loc,
    const float* __restrict__ text_feat,
    const float* __restrict__ ent_mem,
    const int*   __restrict__ count,
    float* __restrict__ ws)
{
    __shared__ float s_val[1024];
    __shared__ int   s_idx[1024];
    __shared__ float s_red[1024];
    __shared__ float s_cos[L_TOK];
    __shared__ float s_w[L_TOK];

    const int tid = threadIdx.x;

    // ---- Phase 1: argmax (first-index ties) + entropy over init_pred ----
    float best = -INFINITY; int bidx = 0x7fffffff;
    float entacc = 0.0f;
    for (int i = tid; i < C_CLS; i += 1024) {
        float p = init_pred[i];
        entacc -= p * logf(p + 1e-8f);
        if (p > best || (p == best && i < bidx)) { best = p; bidx = i; }
    }
    s_val[tid] = best; s_idx[tid] = bidx; s_red[tid] = entacc;
    __syncthreads();
    for (int s = 512; s > 0; s >>= 1) {
        if (tid < s) {
            float v2 = s_val[tid + s]; int i2 = s_idx[tid + s];
            if (v2 > s_val[tid] || (v2 == s_val[tid] && i2 < s_idx[tid])) {
                s_val[tid] = v2; s_idx[tid] = i2;
            }
            s_red[tid] += s_red[tid + s];
        }
        __syncthreads();
    }
    const int   pseudo = s_idx[0];
    const float value  = s_val[0];
    const float ent    = s_red[0];

    const float* t = text_feat + (size_t)pseudo * D_DIM;

    // ---- Phase 2: cos[l] = loc[l] . t  (16 waves, one row per wave) ----
    const int wave = tid >> 6, lane = tid & 63;
    for (int l = wave; l < L_TOK; l += 16) {
        const float* row = loc + (size_t)l * D_DIM;
        float acc = 0.0f;
        #pragma unroll
        for (int q = 0; q < D_DIM / 64; ++q) acc += row[lane + q * 64] * t[lane + q * 64];
        #pragma unroll
        for (int off = 32; off > 0; off >>= 1) acc += __shfl_down(acc, off);
        if (lane == 0) s_cos[l] = acc;
    }
    __syncthreads();   // also separates the s_red[0] read above from the rewrite below

    // ---- Phase 3: softmax over 196 logits ----
    float m = (tid < L_TOK) ? s_cos[tid] * SOFTMAX_LOCAL_F : -INFINITY;
    s_red[tid] = m; __syncthreads();
    for (int s = 512; s > 0; s >>= 1) {
        if (tid < s) s_red[tid] = fmaxf(s_red[tid], s_red[tid + s]);
        __syncthreads();
    }
    const float mx = s_red[0];
    __syncthreads();
    float sacc = 0.0f;
    if (tid < L_TOK) {
        float e = expf(s_cos[tid] * SOFTMAX_LOCAL_F - mx);
        s_w[tid] = e; sacc = e;
    }
    s_red[tid] = sacc; __syncthreads();
    for (int s = 512; s > 0; s >>= 1) {
        if (tid < s) s_red[tid] += s_red[tid + s];
        __syncthreads();
    }
    const float inv_sum = 1.0f / s_red[0];
    __syncthreads();

    // ---- Phase C: att[d] = inv_sum * sum_l w[l] * loc[l][d] (1024-wide, coalesced) ----
    float a = 0.0f;
    for (int l = 0; l < L_TOK; ++l) a += s_w[l] * loc[(size_t)l * D_DIM + tid];
    a *= inv_sum;
    s_red[tid] = a * a; __syncthreads();
    for (int s = 512; s > 0; s >>= 1) {
        if (tid < s) s_red[tid] += s_red[tid + s];
        __syncthreads();
    }
    const float inv_norm = rsqrtf(s_red[0]);
    ws[256 + tid] = a * inv_norm;

    // ---- Phase 4: slot / do_write decision (thread 0, exact tie semantics) ----
    if (tid == 0) {
        const int cnt = count[pseudo];
        const bool full = cnt >= M_MEM;
        const float* erow = ent_mem + (size_t)pseudo * M_MEM;
        float emax = erow[0]; int worst = 0;
        for (int j = 1; j < M_MEM; ++j) {
            float e = erow[j];
            if (e > emax) { emax = e; worst = j; }   // strict > => first max index
        }
        const bool replace_ok = ent < emax;
        const bool do_write = (value > 0.0f) && (full ? replace_ok : true);
        int slot = full ? worst : min(max(cnt, 0), M_MEM - 1);
        int* wsi = (int*)ws;
        wsi[0] = pseudo; wsi[1] = slot; wsi[2] = do_write ? 1 : 0;
    }
}

// Block 0: prep (decision + att vector -> ws).
// Blocks 1..2000: unconditional bank->out copy (no dependence on prep).
// Copy loop: 4-deep batched NT loads/stores for memory-level parallelism.
__global__ __launch_bounds__(1024) void fused_kernel(
    const float* __restrict__ init_pred,
    const float* __restrict__ loc,
    const float* __restrict__ text_feat,
    const float* __restrict__ ent_mem,
    const int*   __restrict__ count,
    const f32x4* __restrict__ img,
    const f32x4* __restrict__ locm,
    f32x4* __restrict__ out,
    float* __restrict__ ws)
{
    if (blockIdx.x == 0) {
        prep_body(init_pred, loc, text_feat, ent_mem, count, ws);
        return;
    }
    const int bid  = blockIdx.x - 1;                 // 0..1999
    const int c    = bid >> 1;
    const int half = bid & 1;
    const int n    = M_MEM * D_DIM / 4;              // 12800 f32x4 per chunk
    const int tid  = threadIdx.x;

    const f32x4* src = (half ? locm : img) + (size_t)c * n;
    f32x4* dst = out + (size_t)c * (2 * n) + (size_t)half * n;

    // 12 full iterations as 3 batches of 4 independent load/store pairs,
    // then a 512-thread tail (12800 = 12*1024 + 512).
    #pragma unroll
    for (int k = 0; k < 3; ++k) {
        const int base = tid + k * 4096;
        f32x4 v0 = __builtin_nontemporal_load(src + base);
        f32x4 v1 = __builtin_nontemporal_load(src + base + 1024);
        f32x4 v2 = __builtin_nontemporal_load(src + base + 2048);
        f32x4 v3 = __builtin_nontemporal_load(src + base + 3072);
        __builtin_nontemporal_store(v0, dst + base);
        __builtin_nontemporal_store(v1, dst + base + 1024);
        __builtin_nontemporal_store(v2, dst + base + 2048);
        __builtin_nontemporal_store(v3, dst + base + 3072);
    }
    if (tid < 512) {
        const int i = 12288 + tid;
        __builtin_nontemporal_store(__builtin_nontemporal_load(src + i), dst + i);
    }
}

// Patch the two affected 4 KB rows after prep's decision is known.
__global__ __launch_bounds__(256) void row_write_kernel(
    const f32x4* __restrict__ g,           // [D/4]
    const float* __restrict__ ws,
    f32x4* __restrict__ out)
{
    const int* wsi = (const int*)ws;
    if (!wsi[2]) return;
    const int pseudo = wsi[0], slot = wsi[1];
    const f32x4* att = (const f32x4*)(ws + 256);
    f32x4* base = out + (size_t)pseudo * (2 * M_MEM * D_DIM / 4);
    const int tid = threadIdx.x;   // 256 threads x f32x4 = 1024 floats = one row
    base[(size_t)slot * (D_DIM / 4) + tid]           = g[tid];
    base[(size_t)(M_MEM + slot) * (D_DIM / 4) + tid] = att[tid];
}

extern "C" void kernel_launch(void* const* d_in, const int* in_sizes, int n_in,
                              void* d_out, int out_size, void* d_ws, size_t ws_size,
                              hipStream_t stream) {
    const float* init_pred = (const float*)d_in[0];   // (1, C)
    const float* g         = (const float*)d_in[1];   // (1, D)
    const float* loc       = (const float*)d_in[2];   // (1, L, D)
    const float* text_feat = (const float*)d_in[3];   // (C, D)
    const float* img_mem   = (const float*)d_in[4];   // (C, M, D)
    const float* loc_mem   = (const float*)d_in[5];   // (C, M, D)
    const float* ent_mem   = (const float*)d_in[6];   // (C, M)
    const int*   count     = (const int*)d_in[7];     // (C, 1)
    float* out = (float*)d_out;
    float* ws  = (float*)d_ws;

    fused_kernel<<<2 * C_CLS + 1, 1024, 0, stream>>>(
        init_pred, loc, text_feat, ent_mem, count,
        (const f32x4*)img_mem, (const f32x4*)loc_mem, (f32x4*)out, ws);
    row_write_kernel<<<1, 256, 0, stream>>>((const f32x4*)g, ws, (f32x4*)out);
}